// Round 5
// baseline (125.549 us; speedup 1.0000x reference)
//
#include <hip/hip_runtime.h>

#define NT1 512
#define NT2 256

struct WPtrs { const float* W[7]; const float* Bv[7]; };

// K1 state swizzle on 16B-chunk index (R2-proven: conflicts 1.57e7 -> 1.3e5)
__device__ __forceinline__ int swz(int ci) {
  return ci ^ (((ci >> 3) ^ (ci >> 6) ^ (ci >> 9)) & 7);
}
// K2 state swizzle: layout [b][16 chunks]; fold batch bits into bank-group bits
__device__ __forceinline__ int scr(int ci) { return ci ^ ((ci >> 4) & 7); }

// ---------------- K1: input conv + levels 1..7 ----------------
// 4 output channels per thread (th = tid&1 selects ch quad), 2 threads/child.
// Per item: 4 ds_read_b128 + 64 FMA + 1 ds_write_b128.
__global__ __launch_bounds__(NT1, 2) void bfly_k1(
    const float* __restrict__ x, const float* __restrict__ F,
    const float* __restrict__ fbias, WPtrs P, float* __restrict__ ws)
{
  __shared__ float4 sA[2048];
  __shared__ float4 sB[2048];
  const int tid = threadIdx.x;
  const int b = blockIdx.x;
  const int th = tid & 1;         // channel quad: ch 4*th .. 4*th+3
  const int g  = tid >> 1;        // 256 work groups

  // phase 1: input conv (kernel=16, stride=16)
  {
    float4 fw[16];
#pragma unroll
    for (int f = 0; f < 16; ++f) fw[f] = *(const float4*)(F + f * 8 + th * 4);
    float4 bias = *(const float4*)(fbias + th * 4);
    const float* xb = x + (size_t)b * 16384;
#pragma unroll 1
    for (int i = 0; i < 4; ++i) {
      int n = g + i * 256;
      const float4* xr = (const float4*)(xb + n * 16);
      float xin[16];
#pragma unroll
      for (int q = 0; q < 4; ++q) {
        float4 v = xr[q];
        xin[4*q]=v.x; xin[4*q+1]=v.y; xin[4*q+2]=v.z; xin[4*q+3]=v.w;
      }
      float4 a = bias;
#pragma unroll
      for (int f = 0; f < 16; ++f) {
        a.x += xin[f]*fw[f].x; a.y += xin[f]*fw[f].y;
        a.z += xin[f]*fw[f].z; a.w += xin[f]*fw[f].w;
      }
      sA[swz(2*n + th)] = make_float4(fmaxf(a.x,0.f), fmaxf(a.y,0.f),
                                      fmaxf(a.z,0.f), fmaxf(a.w,0.f));
    }
  }
  __syncthreads();

  // levels 1..7: flat row p = t*K + k; child (k,t) reads parents
  // p0 = 2t*Kp + (k>>1), p1 = p0 + Kp.
  float4* src = sA; float4* dst = sB;
#pragma unroll 1
  for (int lvl = 1; lvl <= 7; ++lvl) {
    const int K = 1 << lvl, Kp = K >> 1, G = 256 >> lvl;   // K<=128 < 256 groups
    const int k = g & (K - 1), tIdx = g >> lvl;
    const float* Wl = P.W[lvl-1];
    float4 w4[16];                       // [s*8+c] -> W[k][s][c][4th..4th+3]
#pragma unroll
    for (int s = 0; s < 2; ++s)
#pragma unroll
      for (int c = 0; c < 8; ++c)
        w4[s*8+c] = *(const float4*)(Wl + k*128 + s*64 + c*8 + th*4);
    float4 bias = *(const float4*)(P.Bv[lvl-1] + k*8 + th*4);
    const int kp = k >> 1;
#pragma unroll 1
    for (int i = 0; i < 4; ++i) {
      int t = tIdx + i * G;
      int p0 = 2*t*Kp + kp, p1 = p0 + Kp;
      float4 A0 = src[swz(2*p0)], A1 = src[swz(2*p0+1)];
      float4 C0 = src[swz(2*p1)], C1 = src[swz(2*p1+1)];
      float pa[8] = {A0.x,A0.y,A0.z,A0.w,A1.x,A1.y,A1.z,A1.w};
      float pb[8] = {C0.x,C0.y,C0.z,C0.w,C1.x,C1.y,C1.z,C1.w};
      float4 a = bias;
#pragma unroll
      for (int c = 0; c < 8; ++c) {
        a.x += pa[c]*w4[c].x + pb[c]*w4[8+c].x;
        a.y += pa[c]*w4[c].y + pb[c]*w4[8+c].y;
        a.z += pa[c]*w4[c].z + pb[c]*w4[8+c].z;
        a.w += pa[c]*w4[c].w + pb[c]*w4[8+c].w;
      }
      int r = t*K + k;
      dst[swz(2*r + th)] = make_float4(fmaxf(a.x,0.f), fmaxf(a.y,0.f),
                                       fmaxf(a.z,0.f), fmaxf(a.w,0.f));
    }
    __syncthreads();
    float4* tmp = src; src = dst; dst = tmp;
  }

  // copy level-7 state to ws as [j][b][t7][c] (j = level-7 branch = row % 128)
#pragma unroll 1
  for (int o = tid; o < 2048; o += NT1) {
    int j = o >> 4, t = (o >> 1) & 7, h = o & 1;
    float4 v = src[swz(2*(t*128 + j) + h)];
    *(float4*)(ws + (size_t)j*65536 + b*64 + t*8 + h*4) = v;
  }
}

// ---------------- K2: levels 8..10 + dense, weight-stationary ----------------
// block = (j, 32-batch tile). All of j's subtree weights staged in LDS once.
// 4 channels per thread (th), 2 threads/child.
__global__ __launch_bounds__(NT2, 4) void bfly_k2(
    const float* __restrict__ ws,
    const float* __restrict__ W8, const float* __restrict__ B8,
    const float* __restrict__ W9, const float* __restrict__ B9,
    const float* __restrict__ W10, const float* __restrict__ B10,
    const float* __restrict__ fea, float* __restrict__ out)
{
  __shared__ float4 sA[512], sB[512];    // 32 batches x 16 chunks, ping-pong
  __shared__ float swt[2928];            // W8|W9|W10|B8|B9|B10|FEA
  const int tid = threadIdx.x;
  const int j = blockIdx.x, b0 = blockIdx.y * 32;
  const int th = tid & 1, g = tid >> 1;  // 128 groups

  // stage level-7 state (8KB contiguous)
  {
    const float4* s4 = (const float4*)(ws + (size_t)j*65536 + (size_t)b0*64);
#pragma unroll
    for (int it = 0; it < 2; ++it) {
      int idx = tid + it*256;            // b_l*16 + chunk
      sA[scr(idx)] = s4[idx];
    }
  }
  // stage weights (contiguous f4 blocks)
  {
    float4* d = (float4*)swt;
    for (int i = tid; i < 64;  i += NT2) d[i]       = ((const float4*)(W8  + j*256 ))[i];
    for (int i = tid; i < 128; i += NT2) d[64+i]    = ((const float4*)(W9  + j*512 ))[i];
    for (int i = tid; i < 256; i += NT2) d[192+i]   = ((const float4*)(W10 + j*1024))[i];
    if (tid < 4)  d[448+tid] = ((const float4*)(B8  + j*16))[tid];
    if (tid < 8)  d[452+tid] = ((const float4*)(B9  + j*32))[tid];
    if (tid < 16) d[460+tid] = ((const float4*)(B10 + j*64))[tid];
    for (int i = tid; i < 256; i += NT2) d[476+i]   = ((const float4*)(fea + j*1024))[i];
  }
  __syncthreads();

  auto loadW = [&](int woff, int boff, int k_l, float4* w4, float4& bias) {
#pragma unroll
    for (int s = 0; s < 2; ++s)
#pragma unroll
      for (int c = 0; c < 8; ++c)
        w4[s*8+c] = *(const float4*)(swt + woff + k_l*128 + s*64 + c*8 + th*4);
    bias = *(const float4*)(swt + boff + k_l*8 + th*4);
  };
  auto doItem = [&](const float4* S, float4* D, const float4* w4, float4 bias,
                    int k_l, int bl, int t, int KL, int KPL) {
    int p0 = 2*t*KPL + (k_l >> 1), p1 = p0 + KPL;
    int base = bl * 16;
    float4 A0 = S[scr(base + 2*p0)], A1 = S[scr(base + 2*p0 + 1)];
    float4 C0 = S[scr(base + 2*p1)], C1 = S[scr(base + 2*p1 + 1)];
    float pa[8] = {A0.x,A0.y,A0.z,A0.w,A1.x,A1.y,A1.z,A1.w};
    float pb[8] = {C0.x,C0.y,C0.z,C0.w,C1.x,C1.y,C1.z,C1.w};
    float4 a = bias;
#pragma unroll
    for (int c = 0; c < 8; ++c) {
      a.x += pa[c]*w4[c].x + pb[c]*w4[8+c].x;
      a.y += pa[c]*w4[c].y + pb[c]*w4[8+c].y;
      a.z += pa[c]*w4[c].z + pb[c]*w4[8+c].z;
      a.w += pa[c]*w4[c].w + pb[c]*w4[8+c].w;
    }
    int r = t*KL + k_l;
    D[scr(base + 2*r + th)] = make_float4(fmaxf(a.x,0.f), fmaxf(a.y,0.f),
                                          fmaxf(a.z,0.f), fmaxf(a.w,0.f));
  };

  { // level 8: sA(v7) -> sB ; local K=2, Kp=1, T=4
    int k_l = g & 1, bl = (g >> 1) & 31, t0 = (g >> 6) * 2;
    float4 w4[16], bias; loadW(0, 1792, k_l, w4, bias);
#pragma unroll
    for (int it = 0; it < 2; ++it) doItem(sA, sB, w4, bias, k_l, bl, t0 + it, 2, 1);
  }
  __syncthreads();
  { // level 9: sB -> sA ; K=4, Kp=2, T=2
    int k_l = g & 3, bl = g >> 2;
    float4 w4[16], bias; loadW(256, 1808, k_l, w4, bias);
#pragma unroll
    for (int it = 0; it < 2; ++it) doItem(sB, sA, w4, bias, k_l, bl, it, 4, 2);
  }
  __syncthreads();
  { // level 10: sA -> sB ; K=8, Kp=4, T=1
    int k_l = g & 7, bo = g >> 3;
    float4 w4[16], bias; loadW(768, 1840, k_l, w4, bias);
#pragma unroll
    for (int it = 0; it < 2; ++it) doItem(sA, sB, w4, bias, k_l, bo + it*16, 0, 8, 4);
  }
  __syncthreads();
  { // dense: out[b, (8j+k)*16+f] = sum_c v10[k][c] * fea[8j+k][c][f]
    int ch = tid & 7, b_l = tid >> 3;    // 8 chunks x 32 batches
    float* op = out + ((size_t)(b0 + b_l)) * 16384 + j * 128;
#pragma unroll
    for (int it = 0; it < 4; ++it) {
      int cc = ch + it*8, k = cc >> 2, fq = cc & 3;
      float4 s0 = sB[scr(b_l*16 + k*2)];
      float4 s1 = sB[scr(b_l*16 + k*2 + 1)];
      float sc[8] = {s0.x,s0.y,s0.z,s0.w,s1.x,s1.y,s1.z,s1.w};
      float4 acc = make_float4(0.f, 0.f, 0.f, 0.f);
#pragma unroll
      for (int c = 0; c < 8; ++c) {
        float4 fv = *(const float4*)(swt + 1904 + k*128 + c*16 + fq*4);
        acc.x += sc[c]*fv.x; acc.y += sc[c]*fv.y;
        acc.z += sc[c]*fv.z; acc.w += sc[c]*fv.w;
      }
      *(float4*)(op + k*16 + fq*4) = acc;
    }
  }
}

extern "C" void kernel_launch(void* const* d_in, const int* in_sizes, int n_in,
                              void* d_out, int out_size, void* d_ws, size_t ws_size,
                              hipStream_t stream) {
  const float* x  = (const float*)d_in[0];
  const float* F  = (const float*)d_in[1];
  const float* fb = (const float*)d_in[2];
  WPtrs P;
  for (int l = 0; l < 7; ++l) {
    P.W[l]  = (const float*)d_in[3 + 2 * l];
    P.Bv[l] = (const float*)d_in[4 + 2 * l];
  }
  const float* W8  = (const float*)d_in[17];
  const float* B8  = (const float*)d_in[18];
  const float* W9  = (const float*)d_in[19];
  const float* B9  = (const float*)d_in[20];
  const float* W10 = (const float*)d_in[21];
  const float* B10 = (const float*)d_in[22];
  const float* fea = (const float*)d_in[23];
  float* ws = (float*)d_ws;   // 128*1024*64 floats = 33.5 MB
  float* out = (float*)d_out;

  bfly_k1<<<dim3(1024), dim3(NT1), 0, stream>>>(x, F, fb, P, ws);
  bfly_k2<<<dim3(128, 32), dim3(NT2), 0, stream>>>(ws, W8, B8, W9, B9, W10, B10, fea, out);
}